// Round 2
// baseline (726.022 us; speedup 1.0000x reference)
//
#include <hip/hip_runtime.h>

// HEALPix padding, specialized to the bench setup:
//   x: [B=1, F=12, C=128, H=256, W=256] float32, pad=1, channels_last=0
//   out: [1, 12, 128, 258, 258] float32
//
// v3: split interior (bulk, 98.5%) from halo (1.5%).
//   - Interior: one block = 4 rows of one plane (1 row per wave). Fully
//     coalesced contiguous dword loads+stores: lane i copies elements
//     {i, i+64, i+128, i+192} of the row, so every memory instruction
//     covers one contiguous 256B segment. (Output row interior starts at
//     an odd element offset -> no aligned wide stores possible.)
//     Zero integer divisions on this path.
//   - Halo: harness-verified gather logic (previous session), on a small
//     dedicated block range after the interior blocks.

constexpr int H  = 256;
constexpr int W  = 256;
constexpr int P  = 1;
constexpr int HP = H + 2 * P;   // 258
constexpr int WP = W + 2 * P;   // 258
constexpr int C  = 128;
constexpr int IN_PLANE  = H * W;     // 65536
constexpr int OUT_PLANE = HP * WP;   // 66564
constexpr int NPLANES   = 12 * C;    // 1536 (B == 1)

constexpr int ROWS_PER_BLOCK  = 4;
constexpr int INTERIOR_BLOCKS = NPLANES * (H / ROWS_PER_BLOCK);   // 98304
constexpr int HALO_PER_PLANE  = 2 * WP + 2 * H;                   // 1028
constexpr int TOTAL_HALO      = NPLANES * HALO_PER_PLANE;         // 1579008
constexpr int HALO_BLOCKS     = (TOTAL_HALO + 255) / 256;         // 6168

__global__ __launch_bounds__(256) void healpix_pad_kernel(
    const float* __restrict__ in, float* __restrict__ out)
{
    const int b = blockIdx.x;

    if (b < INTERIOR_BLOCKS) {
        // ---------------- interior: pure coalesced copy ----------------
        const int n    = b >> 6;          // plane index (64 blocks per plane)
        const int rg   = b & 63;          // row group within plane
        const int t    = threadIdx.x;
        const int r    = t >> 6;          // 0..3 row within group (one per wave)
        const int lane = t & 63;
        const int y    = rg * ROWS_PER_BLOCK + r;   // input row 0..255

        const float* srow = in  + (size_t)n * IN_PLANE  + (size_t)y * W;
        float*       orow = out + (size_t)n * OUT_PLANE + (size_t)(y + P) * WP + P;

        #pragma unroll
        for (int k = 0; k < 4; ++k) {
            const float v = __builtin_nontemporal_load(srow + k * 64 + lane);
            __builtin_nontemporal_store(v, orow + k * 64 + lane);
        }
        return;
    }

    // ---------------- halo: gather from neighbor faces ----------------
    const int h = (b - INTERIOR_BLOCKS) * 256 + threadIdx.x;
    if (h >= TOTAL_HALO) return;

    const int n   = h / HALO_PER_PLANE;           // plane index
    const int rem = h - n * HALO_PER_PLANE;

    int y, x;
    if      (rem < WP)          { y = 0;          x = rem; }
    else if (rem < 2 * WP)      { y = HP - 1;     x = rem - WP; }
    else if (rem < 2 * WP + H)  { x = 0;          y = rem - (2 * WP) + 1; }
    else                        { x = WP - 1;     y = rem - (2 * WP + H) + 1; }

    const int face = n >> 7;                      // n / C
    const long nbase = (long)n * IN_PLANE;
    auto foff = [&](int g) -> long {
        return nbase + (long)(g - face) * C * IN_PLANE;
    };

    float v;
    {
        int ry = (y < P) ? 0 : (y < P + H ? 1 : 2);
        int rx = (x < P) ? 0 : (x < P + W ? 1 : 2);
        int my = y - P, mx = x - P;          // middle-region locals
        int ty = y,      tx = x;             // top/left-region locals [0,P)
        int by = y - P - H, bx = x - P - W;  // bottom/right-region locals [0,P)

        if (face < 4) {
            // -------- northern polar faces --------
            int i  = face;
            int t  = (i + 1) & 3;
            int tl = (i + 2) & 3;
            int l  = (i + 3) & 3;
            int bl = l;
            int bb = i + 4;
            int br = i + 8;
            int r  = 4 + ((i + 1) & 3);
            int tr = t;
            int g, yy, xx;
            if      (ry == 0 && rx == 1) { g = t;  yy = mx;          xx = P - 1 - ty; } // rot(t,1)[-p:,:]
            else if (ry == 2 && rx == 1) { g = bb; yy = by;          xx = mx;         }
            else if (ry == 0 && rx == 0) { g = tl; yy = P - 1 - ty;  xx = P - 1 - tx; } // rot(tl,2)
            else if (ry == 1 && rx == 0) { g = l;  yy = P - 1 - tx;  xx = my;         } // rot(l,-1)
            else if (ry == 2 && rx == 0) { g = bl; yy = by;          xx = W - P + tx; }
            else if (ry == 0 && rx == 2) { g = tr; yy = bx;          xx = P - 1 - ty; } // rot(tr,1)
            else if (ry == 1 && rx == 2) { g = r;  yy = my;          xx = bx;         }
            else                         { g = br; yy = by;          xx = bx;         }
            v = in[foff(g) + yy * W + xx];
        } else if (face < 8) {
            // -------- equatorial faces --------
            int i  = face - 4;
            int t  = i;
            int l  = (i + 3) & 3;
            int bl = 4 + ((i + 3) & 3);
            int bb = 8 + i;
            int r  = 8 + ((i + 3) & 3);
            int tr = 4 + ((i + 1) & 3);
            if      (ry == 0 && rx == 1) { v = in[foff(t)  + (H - P + ty) * W + mx]; }
            else if (ry == 2 && rx == 1) { v = in[foff(bb) + by * W + mx]; }
            else if (ry == 1 && rx == 0) { v = in[foff(l)  + my * W + (W - P + tx)]; }
            else if (ry == 2 && rx == 0) { v = in[foff(bl) + by * W + (W - P + tx)]; }
            else if (ry == 0 && rx == 2) { v = in[foff(tr) + (H - P + ty) * W + bx]; }
            else if (ry == 1 && rx == 2) { v = in[foff(r)  + my * W + bx]; }
            else if (ry == 0 && rx == 0) {
                // tl corner block (average point + continued edges for p>1)
                if      (ty == P - 1 && tx == P - 1)
                    v = 0.5f * in[foff(t) + (H - 1) * W + 0] +
                        0.5f * in[foff(l) + 0 * W + (W - 1)];
                else if (ty == P - 1) v = in[foff(l) + 0 * W + (W - P + tx)];
                else if (tx == P - 1) v = in[foff(t) + (H - P + ty) * W + 0];
                else                  v = 0.0f;
            } else {
                // br corner block
                if      (by == 0 && bx == 0)
                    v = 0.5f * in[foff(bb) + 0 * W + (W - 1)] +
                        0.5f * in[foff(r)  + (H - 1) * W + 0];
                else if (by == 0) v = in[foff(r)  + (H - 1) * W + bx];
                else if (bx == 0) v = in[foff(bb) + by * W + (W - 1)];
                else              v = 0.0f;
            }
        } else {
            // -------- southern polar faces --------
            int i  = face - 8;
            int t  = 4 + ((i + 1) & 3);
            int tl = i;
            int l  = 4 + i;
            int bl = 8 + ((i + 3) & 3);
            int bb = bl;
            int br = 8 + ((i + 2) & 3);
            int r  = 8 + ((i + 1) & 3);
            int tr = r;
            int g, yy, xx;
            if      (ry == 0 && rx == 1) { g = t;  yy = H - P + ty; xx = mx;         }
            else if (ry == 2 && rx == 1) { g = bb; yy = mx;         xx = W - 1 - by; } // rot(b,1)
            else if (ry == 0 && rx == 0) { g = tl; yy = H - P + ty; xx = W - P + tx; }
            else if (ry == 1 && rx == 0) { g = l;  yy = my;         xx = W - P + tx; }
            else if (ry == 2 && rx == 0) { g = bl; yy = W - P + tx; xx = W - 1 - by; } // rot(bl,1)
            else if (ry == 0 && rx == 2) { g = tr; yy = H - 1 - bx; xx = H - P + ty; } // rot(tr,-1)
            else if (ry == 1 && rx == 2) { g = r;  yy = H - 1 - bx; xx = my;         } // rot(r,-1)
            else                         { g = br; yy = H - 1 - by; xx = W - 1 - bx; } // rot(br,2)
            v = in[foff(g) + yy * W + xx];
        }
    }
    out[(size_t)n * OUT_PLANE + (size_t)y * WP + x] = v;
}

extern "C" void kernel_launch(void* const* d_in, const int* in_sizes, int n_in,
                              void* d_out, int out_size, void* d_ws, size_t ws_size,
                              hipStream_t stream) {
    const float* in = (const float*)d_in[0];
    float* out = (float*)d_out;
    const int blocks = INTERIOR_BLOCKS + HALO_BLOCKS;   // 104472
    healpix_pad_kernel<<<blocks, 256, 0, stream>>>(in, out);
}

// Round 3
// 701.875 us; speedup vs baseline: 1.0344x; 1.0344x over previous
//
#include <hip/hip_runtime.h>

// HEALPix padding, specialized to the bench setup:
//   x: [B=1, F=12, C=128, H=256, W=256] float32, pad=1, channels_last=0
//   out: [1, 12, 128, 258, 258] float32
//
// v4: halo blocks FIRST (overlap their divergent, scattered gathers with the
//     interior stream instead of serializing them as a tail), interior blocks
//     after, 8 rows per interior block (2 per wave) to halve block count.
//   - Interior: fully coalesced contiguous dword loads+stores: lane i copies
//     elements {i, i+64, i+128, i+192} of a row, so every memory instruction
//     covers one contiguous 256B segment. (Output row interior starts at an
//     odd element offset -> no aligned wide stores possible.) Nontemporal on
//     both sides; zero integer divisions on this path.
//   - Halo: harness-verified gather logic (unchanged since v2/v3 pass).

constexpr int H  = 256;
constexpr int W  = 256;
constexpr int P  = 1;
constexpr int HP = H + 2 * P;   // 258
constexpr int WP = W + 2 * P;   // 258
constexpr int C  = 128;
constexpr int IN_PLANE  = H * W;     // 65536
constexpr int OUT_PLANE = HP * WP;   // 66564
constexpr int NPLANES   = 12 * C;    // 1536 (B == 1)

constexpr int ROWS_PER_BLOCK  = 8;
constexpr int BLOCKS_PER_PLANE = H / ROWS_PER_BLOCK;              // 32
constexpr int INTERIOR_BLOCKS = NPLANES * BLOCKS_PER_PLANE;       // 49152
constexpr int HALO_PER_PLANE  = 2 * WP + 2 * H;                   // 1028
constexpr int TOTAL_HALO      = NPLANES * HALO_PER_PLANE;         // 1579008
constexpr int HALO_BLOCKS     = (TOTAL_HALO + 255) / 256;         // 6168

__global__ __launch_bounds__(256) void healpix_pad_kernel(
    const float* __restrict__ in, float* __restrict__ out)
{
    const int b = blockIdx.x;

    if (b >= HALO_BLOCKS) {
        // ---------------- interior: pure coalesced copy ----------------
        const int ib   = b - HALO_BLOCKS;
        const int n    = ib >> 5;         // plane index (32 blocks per plane)
        const int rg   = ib & 31;         // row group within plane
        const int r    = threadIdx.x >> 6;   // wave 0..3
        const int lane = threadIdx.x & 63;

        const float* pin  = in  + (size_t)n * IN_PLANE;
        float*       pout = out + (size_t)n * OUT_PLANE;

        #pragma unroll
        for (int kr = 0; kr < 2; ++kr) {
            const int y = rg * ROWS_PER_BLOCK + kr * 4 + r;   // input row
            const float* srow = pin  + (size_t)y * W;
            float*       orow = pout + (size_t)(y + P) * WP + P;
            #pragma unroll
            for (int k = 0; k < 4; ++k) {
                const float v = __builtin_nontemporal_load(srow + k * 64 + lane);
                __builtin_nontemporal_store(v, orow + k * 64 + lane);
            }
        }
        return;
    }

    // ---------------- halo: gather from neighbor faces ----------------
    const int h = b * 256 + threadIdx.x;
    if (h >= TOTAL_HALO) return;

    const int n   = h / HALO_PER_PLANE;           // plane index
    const int rem = h - n * HALO_PER_PLANE;

    int y, x;
    if      (rem < WP)          { y = 0;          x = rem; }
    else if (rem < 2 * WP)      { y = HP - 1;     x = rem - WP; }
    else if (rem < 2 * WP + H)  { x = 0;          y = rem - (2 * WP) + 1; }
    else                        { x = WP - 1;     y = rem - (2 * WP + H) + 1; }

    const int face = n >> 7;                      // n / C
    const long nbase = (long)n * IN_PLANE;
    auto foff = [&](int g) -> long {
        return nbase + (long)(g - face) * C * IN_PLANE;
    };

    float v;
    {
        int ry = (y < P) ? 0 : (y < P + H ? 1 : 2);
        int rx = (x < P) ? 0 : (x < P + W ? 1 : 2);
        int my = y - P, mx = x - P;          // middle-region locals
        int ty = y,      tx = x;             // top/left-region locals [0,P)
        int by = y - P - H, bx = x - P - W;  // bottom/right-region locals [0,P)

        if (face < 4) {
            // -------- northern polar faces --------
            int i  = face;
            int t  = (i + 1) & 3;
            int tl = (i + 2) & 3;
            int l  = (i + 3) & 3;
            int bl = l;
            int bb = i + 4;
            int br = i + 8;
            int r  = 4 + ((i + 1) & 3);
            int tr = t;
            int g, yy, xx;
            if      (ry == 0 && rx == 1) { g = t;  yy = mx;          xx = P - 1 - ty; } // rot(t,1)[-p:,:]
            else if (ry == 2 && rx == 1) { g = bb; yy = by;          xx = mx;         }
            else if (ry == 0 && rx == 0) { g = tl; yy = P - 1 - ty;  xx = P - 1 - tx; } // rot(tl,2)
            else if (ry == 1 && rx == 0) { g = l;  yy = P - 1 - tx;  xx = my;         } // rot(l,-1)
            else if (ry == 2 && rx == 0) { g = bl; yy = by;          xx = W - P + tx; }
            else if (ry == 0 && rx == 2) { g = tr; yy = bx;          xx = P - 1 - ty; } // rot(tr,1)
            else if (ry == 1 && rx == 2) { g = r;  yy = my;          xx = bx;         }
            else                         { g = br; yy = by;          xx = bx;         }
            v = in[foff(g) + yy * W + xx];
        } else if (face < 8) {
            // -------- equatorial faces --------
            int i  = face - 4;
            int t  = i;
            int l  = (i + 3) & 3;
            int bl = 4 + ((i + 3) & 3);
            int bb = 8 + i;
            int r  = 8 + ((i + 3) & 3);
            int tr = 4 + ((i + 1) & 3);
            if      (ry == 0 && rx == 1) { v = in[foff(t)  + (H - P + ty) * W + mx]; }
            else if (ry == 2 && rx == 1) { v = in[foff(bb) + by * W + mx]; }
            else if (ry == 1 && rx == 0) { v = in[foff(l)  + my * W + (W - P + tx)]; }
            else if (ry == 2 && rx == 0) { v = in[foff(bl) + by * W + (W - P + tx)]; }
            else if (ry == 0 && rx == 2) { v = in[foff(tr) + (H - P + ty) * W + bx]; }
            else if (ry == 1 && rx == 2) { v = in[foff(r)  + my * W + bx]; }
            else if (ry == 0 && rx == 0) {
                // tl corner block (average point + continued edges for p>1)
                if      (ty == P - 1 && tx == P - 1)
                    v = 0.5f * in[foff(t) + (H - 1) * W + 0] +
                        0.5f * in[foff(l) + 0 * W + (W - 1)];
                else if (ty == P - 1) v = in[foff(l) + 0 * W + (W - P + tx)];
                else if (tx == P - 1) v = in[foff(t) + (H - P + ty) * W + 0];
                else                  v = 0.0f;
            } else {
                // br corner block
                if      (by == 0 && bx == 0)
                    v = 0.5f * in[foff(bb) + 0 * W + (W - 1)] +
                        0.5f * in[foff(r)  + (H - 1) * W + 0];
                else if (by == 0) v = in[foff(r)  + (H - 1) * W + bx];
                else if (bx == 0) v = in[foff(bb) + by * W + (W - 1)];
                else              v = 0.0f;
            }
        } else {
            // -------- southern polar faces --------
            int i  = face - 8;
            int t  = 4 + ((i + 1) & 3);
            int tl = i;
            int l  = 4 + i;
            int bl = 8 + ((i + 3) & 3);
            int bb = bl;
            int br = 8 + ((i + 2) & 3);
            int r  = 8 + ((i + 1) & 3);
            int tr = r;
            int g, yy, xx;
            if      (ry == 0 && rx == 1) { g = t;  yy = H - P + ty; xx = mx;         }
            else if (ry == 2 && rx == 1) { g = bb; yy = mx;         xx = W - 1 - by; } // rot(b,1)
            else if (ry == 0 && rx == 0) { g = tl; yy = H - P + ty; xx = W - P + tx; }
            else if (ry == 1 && rx == 0) { g = l;  yy = my;         xx = W - P + tx; }
            else if (ry == 2 && rx == 0) { g = bl; yy = W - P + tx; xx = W - 1 - by; } // rot(bl,1)
            else if (ry == 0 && rx == 2) { g = tr; yy = H - 1 - bx; xx = H - P + ty; } // rot(tr,-1)
            else if (ry == 1 && rx == 2) { g = r;  yy = H - 1 - bx; xx = my;         } // rot(r,-1)
            else                         { g = br; yy = H - 1 - by; xx = W - 1 - bx; } // rot(br,2)
            v = in[foff(g) + yy * W + xx];
        }
    }
    out[(size_t)n * OUT_PLANE + (size_t)y * WP + x] = v;
}

extern "C" void kernel_launch(void* const* d_in, const int* in_sizes, int n_in,
                              void* d_out, int out_size, void* d_ws, size_t ws_size,
                              hipStream_t stream) {
    const float* in = (const float*)d_in[0];
    float* out = (float*)d_out;
    const int blocks = HALO_BLOCKS + INTERIOR_BLOCKS;   // 55320
    healpix_pad_kernel<<<blocks, 256, 0, stream>>>(in, out);
}